// Round 1
// baseline (945.777 us; speedup 1.0000x reference)
//
#include <hip/hip_runtime.h>

#define EPSN 1e-3f

// Problem constants: B=16, H=W=64, C=512, IC=64. Rows M = B*H*W = 65536.

// ---------------- Kernel 1: [x @ (w_f|w_h)] fused LayerNorm -> g, h ----------
// x: (65536,512), w_f/w_h: (512,64) row-major. Outputs g,h: (65536,64).
// Block: 256 threads, 32 rows/block, K-chunks of 64. LDS ~40KB -> 3 blocks/CU.
__global__ __launch_bounds__(256, 3) void k1_gemm_ln(
    const float* __restrict__ x,
    const float* __restrict__ w_f,
    const float* __restrict__ w_h,
    const float* __restrict__ gamma_f, const float* __restrict__ beta_f,
    const float* __restrict__ gamma_h, const float* __restrict__ beta_h,
    float* __restrict__ g_out, float* __restrict__ h_out)
{
    __shared__ float sA[32 * 64];    // 8 KB  A tile
    __shared__ float sB[64 * 128];   // 32 KB B tile (reused as 32x128 C tile)
    __shared__ float sMean[64];
    __shared__ float sRstd[64];

    const int t = threadIdx.x;
    const int row0 = blockIdx.x * 32;

    const int jj = (t & 31) * 4;   // col 0..124
    const int rr = (t >> 5) * 4;   // row 0..28

    float acc[4][4];
    #pragma unroll
    for (int r = 0; r < 4; ++r)
        #pragma unroll
        for (int c = 0; c < 4; ++c) acc[r][c] = 0.f;

    for (int kc = 0; kc < 512; kc += 64) {
        // A tile 32x64 (coalesced)
        #pragma unroll
        for (int i = 0; i < 8; ++i) {
            int e = t + i * 256;
            int r = e >> 6, c = e & 63;
            sA[e] = x[(size_t)(row0 + r) * 512 + kc + c];
        }
        // B tile 64x128: cols 0..63 = w_f, 64..127 = w_h (coalesced per 64)
        #pragma unroll
        for (int i = 0; i < 32; ++i) {
            int e = t + i * 256;
            int k = e >> 7, j = e & 127;
            sB[e] = (j < 64) ? w_f[(size_t)(kc + k) * 64 + j]
                             : w_h[(size_t)(kc + k) * 64 + (j - 64)];
        }
        __syncthreads();
        #pragma unroll
        for (int k = 0; k < 64; k += 4) {
            float4 b0 = *(const float4*)&sB[(k + 0) * 128 + jj];
            float4 b1 = *(const float4*)&sB[(k + 1) * 128 + jj];
            float4 b2 = *(const float4*)&sB[(k + 2) * 128 + jj];
            float4 b3 = *(const float4*)&sB[(k + 3) * 128 + jj];
            #pragma unroll
            for (int r = 0; r < 4; ++r) {
                float4 av = *(const float4*)&sA[(rr + r) * 64 + k];
                acc[r][0] += av.x * b0.x; acc[r][1] += av.x * b0.y; acc[r][2] += av.x * b0.z; acc[r][3] += av.x * b0.w;
                acc[r][0] += av.y * b1.x; acc[r][1] += av.y * b1.y; acc[r][2] += av.y * b1.z; acc[r][3] += av.y * b1.w;
                acc[r][0] += av.z * b2.x; acc[r][1] += av.z * b2.y; acc[r][2] += av.z * b2.z; acc[r][3] += av.z * b2.w;
                acc[r][0] += av.w * b3.x; acc[r][1] += av.w * b3.y; acc[r][2] += av.w * b3.z; acc[r][3] += av.w * b3.w;
            }
        }
        __syncthreads();
    }

    // Stash C tile (32x128) into sB, then LN per row-half (64 elems each)
    #pragma unroll
    for (int r = 0; r < 4; ++r) {
        *(float4*)&sB[(rr + r) * 128 + jj] =
            make_float4(acc[r][0], acc[r][1], acc[r][2], acc[r][3]);
    }
    __syncthreads();
    if (t < 64) {
        int r = t >> 1, half = t & 1;
        const float* p = &sB[r * 128 + half * 64];
        float s = 0.f, s2 = 0.f;
        #pragma unroll
        for (int i = 0; i < 64; ++i) { float v = p[i]; s += v; s2 += v * v; }
        float mean = s * (1.f / 64.f);
        float var = s2 * (1.f / 64.f) - mean * mean;   // biased, matches jnp.var
        sMean[t] = mean;
        sRstd[t] = rsqrtf(var + EPSN);
    }
    __syncthreads();
    #pragma unroll
    for (int i = 0; i < 16; ++i) {
        int e = t + i * 256;
        int r = e >> 7, j = e & 127;
        int half = j >> 6, ii = j & 63;
        float mean = sMean[r * 2 + half];
        float rstd = sRstd[r * 2 + half];
        float v = (sB[e] - mean) * rstd;
        if (half == 0)
            g_out[(size_t)(row0 + r) * 64 + ii] = v * gamma_f[ii] + beta_f[ii];
        else
            h_out[(size_t)(row0 + r) * 64 + ii] = v * gamma_h[ii] + beta_h[ii];
    }
}

// ---------------- Kernel 2: softmax over H of f*g, times h -> t --------------
// One block per (b,w). s[hh,i] = g[b,w,hh,i] * g[b,hh,w,i]; softmax over hh;
// t[b,hh,w,i] = a * h[b,hh,w,i]. t stored in GEMM2 row layout (contiguous IC).
__global__ __launch_bounds__(256, 4) void k2_softmax(
    const float* __restrict__ g_in,
    const float* __restrict__ h_in,
    float* __restrict__ t_out)
{
    __shared__ float S[64 * 64];     // 16 KB: s, then exp(s - max)
    __shared__ float Hm[64 * 64];    // 16 KB
    __shared__ float pmax[4 * 64];
    __shared__ float psum[4 * 64];
    __shared__ float colmax[64];
    __shared__ float colinv[64];

    const int t = threadIdx.x;
    const int b = blockIdx.x >> 6;
    const int w = blockIdx.x & 63;

    const size_t base1 = (size_t)(b * 64 + w) * 4096;  // g[b,w,:,:] contiguous

    #pragma unroll
    for (int i = 0; i < 16; ++i) {
        int e = t + i * 256;
        int hh = e >> 6, ii = e & 63;
        size_t idx2 = ((size_t)((b * 64 + hh) * 64 + w)) * 64 + ii;
        S[e]  = g_in[base1 + e] * g_in[idx2];
        Hm[e] = h_in[idx2];
    }
    __syncthreads();

    const int q = t >> 6;     // row-quarter 0..3 (16 hh each)
    const int i = t & 63;     // column (IC index)
    float m = -1e30f;
    #pragma unroll
    for (int r = 0; r < 16; ++r)
        m = fmaxf(m, S[(q * 16 + r) * 64 + i]);
    pmax[q * 64 + i] = m;
    __syncthreads();
    if (t < 64)
        colmax[i] = fmaxf(fmaxf(pmax[i], pmax[64 + i]),
                          fmaxf(pmax[128 + i], pmax[192 + i]));
    __syncthreads();
    const float cm = colmax[i];
    float s = 0.f;
    #pragma unroll
    for (int r = 0; r < 16; ++r) {
        int idx = (q * 16 + r) * 64 + i;
        float e = __expf(S[idx] - cm);
        S[idx] = e;
        s += e;
    }
    psum[q * 64 + i] = s;
    __syncthreads();
    if (t < 64)
        colinv[i] = 1.f / (psum[i] + psum[64 + i] + psum[128 + i] + psum[192 + i]);
    __syncthreads();
    const float ci = colinv[i];
    #pragma unroll
    for (int r = 0; r < 16; ++r) {
        int hh = q * 16 + r;
        int idx = hh * 64 + i;
        t_out[((size_t)((b * 64 + hh) * 64 + w)) * 64 + i] = S[idx] * ci * Hm[idx];
    }
}

// ---------------- Kernel 3: t @ w_fgh, LN, *scale, +x -> out ----------------
// t: (65536,64), w_fgh: (64,512). Block: 16 rows, 256 threads. LDS 68KB.
__global__ __launch_bounds__(256, 2) void k3_gemm_ln_res(
    const float* __restrict__ tmat,
    const float* __restrict__ w_fgh,
    const float* __restrict__ gamma, const float* __restrict__ beta,
    const float* __restrict__ scale,
    const float* __restrict__ x,
    float* __restrict__ out)
{
    __shared__ float sT[16 * 64];     // 4 KB
    __shared__ float sW[64 * 128];    // 32 KB (col chunk of w_fgh)
    __shared__ float sY[16 * 512];    // 32 KB (full y tile for LN)
    __shared__ float pS[16 * 16];
    __shared__ float pS2[16 * 16];
    __shared__ float sStat[32];

    const int t = threadIdx.x;
    const int row0 = blockIdx.x * 16;

    #pragma unroll
    for (int i = 0; i < 4; ++i) {
        int e = t + i * 256;
        sT[e] = tmat[(size_t)row0 * 64 + e];
    }

    const int cg = (t & 31) * 4;   // col in chunk 0..124
    const int rg = (t >> 5) * 2;   // rows, 2 per thread

    for (int cc = 0; cc < 512; cc += 128) {
        #pragma unroll
        for (int i = 0; i < 32; ++i) {
            int e = t + i * 256;
            int k = e >> 7, c = e & 127;
            sW[e] = w_fgh[(size_t)k * 512 + cc + c];
        }
        __syncthreads();
        float acc[2][4] = {{0.f,0.f,0.f,0.f},{0.f,0.f,0.f,0.f}};
        #pragma unroll
        for (int k = 0; k < 64; k += 4) {
            float4 b0 = *(const float4*)&sW[(k + 0) * 128 + cg];
            float4 b1 = *(const float4*)&sW[(k + 1) * 128 + cg];
            float4 b2 = *(const float4*)&sW[(k + 2) * 128 + cg];
            float4 b3 = *(const float4*)&sW[(k + 3) * 128 + cg];
            #pragma unroll
            for (int r = 0; r < 2; ++r) {
                float4 av = *(const float4*)&sT[(rg + r) * 64 + k];
                acc[r][0] += av.x * b0.x; acc[r][1] += av.x * b0.y; acc[r][2] += av.x * b0.z; acc[r][3] += av.x * b0.w;
                acc[r][0] += av.y * b1.x; acc[r][1] += av.y * b1.y; acc[r][2] += av.y * b1.z; acc[r][3] += av.y * b1.w;
                acc[r][0] += av.z * b2.x; acc[r][1] += av.z * b2.y; acc[r][2] += av.z * b2.z; acc[r][3] += av.z * b2.w;
                acc[r][0] += av.w * b3.x; acc[r][1] += av.w * b3.y; acc[r][2] += av.w * b3.z; acc[r][3] += av.w * b3.w;
            }
        }
        #pragma unroll
        for (int r = 0; r < 2; ++r)
            *(float4*)&sY[(rg + r) * 512 + cc + cg] =
                make_float4(acc[r][0], acc[r][1], acc[r][2], acc[r][3]);
        __syncthreads();
    }

    // LN stats over 512 per row: 16 threads/row, 32 elems each, then reduce
    {
        int r = t >> 4, l = t & 15;
        float s = 0.f, s2 = 0.f;
        #pragma unroll
        for (int j = 0; j < 32; ++j) {
            float v = sY[r * 512 + l + j * 16];
            s += v; s2 += v * v;
        }
        pS[t] = s; pS2[t] = s2;
    }
    __syncthreads();
    if (t < 16) {
        float s = 0.f, s2 = 0.f;
        #pragma unroll
        for (int j = 0; j < 16; ++j) { s += pS[t * 16 + j]; s2 += pS2[t * 16 + j]; }
        float mean = s * (1.f / 512.f);
        float var = s2 * (1.f / 512.f) - mean * mean;
        sStat[t * 2] = mean;
        sStat[t * 2 + 1] = rsqrtf(var + EPSN);
    }
    __syncthreads();

    const float sc = scale[0];
    #pragma unroll
    for (int i = 0; i < 8; ++i) {
        int e4 = t + i * 256;
        int r = e4 >> 7, c = (e4 & 127) * 4;
        float mean = sStat[r * 2], rstd = sStat[r * 2 + 1];
        float4 y  = *(const float4*)&sY[r * 512 + c];
        float4 xv = *(const float4*)&x[(size_t)(row0 + r) * 512 + c];
        float4 gm = *(const float4*)&gamma[c];
        float4 bt = *(const float4*)&beta[c];
        float4 o;
        o.x = xv.x + sc * ((y.x - mean) * rstd * gm.x + bt.x);
        o.y = xv.y + sc * ((y.y - mean) * rstd * gm.y + bt.y);
        o.z = xv.z + sc * ((y.z - mean) * rstd * gm.z + bt.z);
        o.w = xv.w + sc * ((y.w - mean) * rstd * gm.w + bt.w);
        *(float4*)&out[(size_t)(row0 + r) * 512 + c] = o;
    }
}

extern "C" void kernel_launch(void* const* d_in, const int* in_sizes, int n_in,
                              void* d_out, int out_size, void* d_ws, size_t ws_size,
                              hipStream_t stream) {
    const float* x         = (const float*)d_in[0];
    const float* w_f       = (const float*)d_in[1];
    const float* w_h       = (const float*)d_in[2];
    const float* w_fgh     = (const float*)d_in[3];
    const float* gamma_f   = (const float*)d_in[4];
    const float* beta_f    = (const float*)d_in[5];
    const float* gamma_h   = (const float*)d_in[6];
    const float* beta_h    = (const float*)d_in[7];
    const float* gamma_fgh = (const float*)d_in[8];
    const float* beta_fgh  = (const float*)d_in[9];
    const float* scale     = (const float*)d_in[10];
    float* out = (float*)d_out;

    float* ws = (float*)d_ws;
    float* g  = ws;                          // 65536*64 floats = 16 MB
    float* h  = ws + (size_t)65536 * 64;     // 16 MB
    float* tm = ws + (size_t)2 * 65536 * 64; // 16 MB

    k1_gemm_ln<<<2048, 256, 0, stream>>>(x, w_f, w_h, gamma_f, beta_f,
                                         gamma_h, beta_h, g, h);
    k2_softmax<<<1024, 256, 0, stream>>>(g, h, tm);
    k3_gemm_ln_res<<<4096, 256, 0, stream>>>(tm, w_fgh, gamma_fgh, beta_fgh,
                                             scale, x, out);
}

// Round 2
// 388.663 us; speedup vs baseline: 2.4334x; 2.4334x over previous
//
#include <hip/hip_runtime.h>

#define EPSN 1e-3f

typedef __attribute__((ext_vector_type(8))) short short8;
typedef __attribute__((ext_vector_type(4))) float floatx4;

// RNE float->bf16 (packed pair / scalar)
__device__ __forceinline__ unsigned f2bf_pack(float a, float b) {
    unsigned ua = __builtin_bit_cast(unsigned, a);
    ua += 0x7FFF + ((ua >> 16) & 1);
    unsigned ub = __builtin_bit_cast(unsigned, b);
    ub += 0x7FFF + ((ub >> 16) & 1);
    return (ua >> 16) | (ub & 0xFFFF0000u);
}
__device__ __forceinline__ unsigned short f2bf(float f) {
    unsigned u = __builtin_bit_cast(unsigned, f);
    u += 0x7FFF + ((u >> 16) & 1);
    return (unsigned short)(u >> 16);
}

// ---------------- Kernel 1: MFMA bf16 [x @ (w_f|w_h)] + fused LN -> g, h -----
// Block: 256 thr (4 waves), 128 rows, N=128 (cols 0..63 = f via w_f, 64..127 = h).
// W (512x128) resident in LDS bf16, B-frag layout. x streamed as double-buffered
// bf16 A-frag tiles (K-chunk 32). Epilogue: C tile -> LDS (stride 129), LN(64).
__global__ __launch_bounds__(256, 1) void k1_gemm_ln(
    const float* __restrict__ x,
    const float* __restrict__ w_f, const float* __restrict__ w_h,
    const float* __restrict__ gamma_f, const float* __restrict__ beta_f,
    const float* __restrict__ gamma_h, const float* __restrict__ beta_h,
    float* __restrict__ g_out, float* __restrict__ h_out)
{
    __shared__ unsigned short Wlds[65536];    // 128 KB: [ntile 8][k8 64][n 16][j 8]
    __shared__ unsigned short Xlds[2][4096];  // 2 x 8 KB: [rt 8][k8 4][m 16][j 8]
    __shared__ float stats[512];              // mean[256], rstd[256]

    const int t = threadIdx.x;
    const int lane = t & 63;
    const int wv = t >> 6;
    const int quad = lane >> 4;
    const int n16 = lane & 15;
    const int wrow = wv >> 1;            // wave grid 2x2: 64 rows x 64 cols each
    const int wcol = wv & 1;
    const int row0 = blockIdx.x * 128;

    // ---- W preload: fp32 -> bf16, B-frag swizzle. 256 wave-iters / 4 waves ----
    #pragma unroll 4
    for (int it = 0; it < 64; ++it) {
        int idx = wv * 64 + it;          // 0..255
        int half = idx >> 7;             // 0: w_f, 1: w_h
        int k4 = idx & 127;              // k = k4*4 + j
        const float* src = (half ? w_h : w_f) + (size_t)(k4 * 4) * 64 + lane;
        float f0 = src[0], f1 = src[64], f2 = src[128], f3 = src[192];
        int ng = half * 64 + lane;       // global col 0..127
        int unit = ((ng >> 4) * 64 + (k4 >> 1)) * 16 + (ng & 15);
        unsigned* dst = (unsigned*)&Wlds[unit * 8 + (k4 & 1) * 4];
        dst[0] = f2bf_pack(f0, f1);
        dst[1] = f2bf_pack(f2, f3);
    }

    // ---- stage chunk 0 ----
    const int srow = t >> 1;             // 0..127
    const int kh = t & 1;                // which 16-k half of the 32-k chunk
    {
        const float4* p = (const float4*)(x + (size_t)(row0 + srow) * 512 + kh * 16);
        float4 q0 = p[0], q1 = p[1], q2 = p[2], q3 = p[3];
        int u0 = ((srow >> 4) * 4 + kh * 2) * 16 + (srow & 15);
        *(uint4*)&Xlds[0][u0 * 8] = make_uint4(
            f2bf_pack(q0.x, q0.y), f2bf_pack(q0.z, q0.w),
            f2bf_pack(q1.x, q1.y), f2bf_pack(q1.z, q1.w));
        *(uint4*)&Xlds[0][(u0 + 16) * 8] = make_uint4(
            f2bf_pack(q2.x, q2.y), f2bf_pack(q2.z, q2.w),
            f2bf_pack(q3.x, q3.y), f2bf_pack(q3.z, q3.w));
    }

    floatx4 acc[4][4];
    #pragma unroll
    for (int rt = 0; rt < 4; ++rt)
        #pragma unroll
        for (int ct = 0; ct < 4; ++ct)
            acc[rt][ct] = (floatx4){0.f, 0.f, 0.f, 0.f};

    // ---- main loop: 16 chunks of K=32, double-buffered ----
    for (int c = 0; c < 16; ++c) {
        float4 q0, q1, q2, q3;
        if (c < 15) {   // issue next chunk's global loads early
            const float4* p = (const float4*)(x + (size_t)(row0 + srow) * 512
                                              + (c + 1) * 32 + kh * 16);
            q0 = p[0]; q1 = p[1]; q2 = p[2]; q3 = p[3];
        }
        __syncthreads();
        const unsigned short* xb = Xlds[c & 1];
        short8 a[4], b[4];
        #pragma unroll
        for (int rt = 0; rt < 4; ++rt)
            a[rt] = *(const short8*)&xb[(((wrow * 4 + rt) * 4 + quad) * 16 + n16) * 8];
        #pragma unroll
        for (int ct = 0; ct < 4; ++ct)
            b[ct] = *(const short8*)&Wlds[(((wcol * 4 + ct) * 64 + c * 4 + quad) * 16 + n16) * 8];
        #pragma unroll
        for (int rt = 0; rt < 4; ++rt)
            #pragma unroll
            for (int ct = 0; ct < 4; ++ct)
                acc[rt][ct] = __builtin_amdgcn_mfma_f32_16x16x32_bf16(
                    a[rt], b[ct], acc[rt][ct], 0, 0, 0);
        if (c < 15) {
            unsigned short* xn = (unsigned short*)Xlds[(c + 1) & 1];
            int u0 = ((srow >> 4) * 4 + kh * 2) * 16 + (srow & 15);
            *(uint4*)&xn[u0 * 8] = make_uint4(
                f2bf_pack(q0.x, q0.y), f2bf_pack(q0.z, q0.w),
                f2bf_pack(q1.x, q1.y), f2bf_pack(q1.z, q1.w));
            *(uint4*)&xn[(u0 + 16) * 8] = make_uint4(
                f2bf_pack(q2.x, q2.y), f2bf_pack(q2.z, q2.w),
                f2bf_pack(q3.x, q3.y), f2bf_pack(q3.z, q3.w));
        }
    }

    // ---- epilogue: C -> LDS (reuse W region), LN per row-half of 64 ----
    __syncthreads();                 // all MFMA ds_reads of Wlds done
    float* Clds = (float*)Wlds;      // 128 x 129 floats = 66 KB <= 128 KB
    #pragma unroll
    for (int rt = 0; rt < 4; ++rt)
        #pragma unroll
        for (int ct = 0; ct < 4; ++ct) {
            int col = wcol * 64 + ct * 16 + n16;
            int rbase = wrow * 64 + rt * 16 + quad * 4;
            floatx4 v = acc[rt][ct];
            #pragma unroll
            for (int r = 0; r < 4; ++r)
                Clds[(rbase + r) * 129 + col] = v[r];
        }
    __syncthreads();
    {
        int r = t >> 1, half = t & 1;
        const float* p = &Clds[r * 129 + half * 64];
        float s = 0.f, s2 = 0.f;
        #pragma unroll
        for (int i = 0; i < 64; ++i) { float v = p[i]; s += v; s2 += v * v; }
        float mean = s * (1.f / 64.f);
        float var = s2 * (1.f / 64.f) - mean * mean;
        stats[t] = mean;                      // index = r*2 + half
        stats[256 + t] = rsqrtf(var + EPSN);
    }
    __syncthreads();
    #pragma unroll 4
    for (int i = 0; i < 64; ++i) {
        int e = t + i * 256;
        int r = e >> 7, j = e & 127;
        int half = j >> 6, ii = j & 63;       // wave-uniform branch (j == t&127)
        float mean = stats[r * 2 + half];
        float rstd = stats[256 + r * 2 + half];
        float v = (Clds[r * 129 + j] - mean) * rstd;
        if (half == 0)
            g_out[(size_t)(row0 + r) * 64 + ii] = v * gamma_f[ii] + beta_f[ii];
        else
            h_out[(size_t)(row0 + r) * 64 + ii] = v * gamma_h[ii] + beta_h[ii];
    }
}

// ---------------- Kernel 2: softmax over H of f*g, times h -> t (bf16, swizzled)
// One block per (b,w). t emitted in MFMA A-frag layout:
// ushort idx = (row>>4)*1024 + (i>>3)*128 + (row&15)*8 + (i&7),  row=(b*64+hh)*64+w
__global__ __launch_bounds__(256, 4) void k2_softmax(
    const float* __restrict__ g_in,
    const float* __restrict__ h_in,
    unsigned short* __restrict__ t_out)
{
    __shared__ float S[64 * 64];
    __shared__ float Hm[64 * 64];
    __shared__ float pmax[4 * 64];
    __shared__ float psum[4 * 64];
    __shared__ float colmax[64];
    __shared__ float colinv[64];

    const int t = threadIdx.x;
    const int b = blockIdx.x >> 6;
    const int w = blockIdx.x & 63;

    const size_t base1 = (size_t)(b * 64 + w) * 4096;

    #pragma unroll
    for (int i = 0; i < 16; ++i) {
        int e = t + i * 256;
        int hh = e >> 6, ii = e & 63;
        size_t idx2 = ((size_t)((b * 64 + hh) * 64 + w)) * 64 + ii;
        S[e]  = g_in[base1 + e] * g_in[idx2];
        Hm[e] = h_in[idx2];
    }
    __syncthreads();

    const int q = t >> 6;
    const int i = t & 63;
    float m = -1e30f;
    #pragma unroll
    for (int r = 0; r < 16; ++r)
        m = fmaxf(m, S[(q * 16 + r) * 64 + i]);
    pmax[q * 64 + i] = m;
    __syncthreads();
    if (t < 64)
        colmax[i] = fmaxf(fmaxf(pmax[i], pmax[64 + i]),
                          fmaxf(pmax[128 + i], pmax[192 + i]));
    __syncthreads();
    const float cm = colmax[i];
    float s = 0.f;
    #pragma unroll
    for (int r = 0; r < 16; ++r) {
        int idx = (q * 16 + r) * 64 + i;
        float e = __expf(S[idx] - cm);
        S[idx] = e;
        s += e;
    }
    psum[q * 64 + i] = s;
    __syncthreads();
    if (t < 64)
        colinv[i] = 1.f / (psum[i] + psum[64 + i] + psum[128 + i] + psum[192 + i]);
    __syncthreads();
    const float ci = colinv[i];
    #pragma unroll
    for (int r = 0; r < 16; ++r) {
        int hh = q * 16 + r;
        int idx = hh * 64 + i;
        int row_g = (b * 64 + hh) * 64 + w;
        float val = S[idx] * ci * Hm[idx];
        t_out[(size_t)(row_g >> 4) * 1024 + (i >> 3) * 128 + (row_g & 15) * 8 + (i & 7)]
            = f2bf(val);
    }
}

// ---------------- Kernel 3: MFMA bf16 t @ w_fgh + LN + scale + residual -------
// Block 256 thr (4 waves), 64 rows (16/wave), full N=512 per wave in acc.
// W_fgh resident in LDS bf16 (B-frag layout); A-frags read straight from the
// swizzled global t. LN(512) via 16-lane shfl_xor reduction. 68 KB LDS -> 2/CU.
__global__ __launch_bounds__(256, 2) void k3_gemm_ln_res(
    const unsigned short* __restrict__ tmat,
    const float* __restrict__ w_fgh,
    const float* __restrict__ gamma, const float* __restrict__ beta,
    const float* __restrict__ scale,
    const float* __restrict__ x,
    float* __restrict__ out)
{
    __shared__ unsigned short Wlds[32768];  // 64 KB: [ntile 32][k8 8][n 16][j 8]
    __shared__ float glds[512], blds[512];

    const int t = threadIdx.x;
    const int lane = t & 63;
    const int wv = t >> 6;
    const int quad = lane >> 4;
    const int n16 = lane & 15;

    glds[t] = gamma[t]; glds[t + 256] = gamma[t + 256];
    blds[t] = beta[t];  blds[t + 256] = beta[t + 256];

    #pragma unroll 4
    for (int it = 0; it < 32; ++it) {
        int idx = wv * 32 + it;          // 0..127 = (k4 0..15) x (nblk 0..7)
        int k4 = idx >> 3;
        int nblk = idx & 7;
        int ng = nblk * 64 + lane;       // global col 0..511
        const float* src = w_fgh + (size_t)(k4 * 4) * 512 + ng;
        float f0 = src[0], f1 = src[512], f2 = src[1024], f3 = src[1536];
        int unit = ((ng >> 4) * 8 + (k4 >> 1)) * 16 + (ng & 15);
        unsigned* dst = (unsigned*)&Wlds[unit * 8 + (k4 & 1) * 4];
        dst[0] = f2bf_pack(f0, f1);
        dst[1] = f2bf_pack(f2, f3);
    }
    __syncthreads();

    const int rowtile = blockIdx.x * 4 + wv;      // 16 rows per wave
    const unsigned short* tb = tmat + (size_t)rowtile * 1024;
    short8 a0 = *(const short8*)&tb[(quad)     * 128 + n16 * 8];   // k 0..31
    short8 a1 = *(const short8*)&tb[(4 + quad) * 128 + n16 * 8];   // k 32..63

    floatx4 acc[32];
    #pragma unroll
    for (int nt = 0; nt < 32; ++nt) acc[nt] = (floatx4){0.f, 0.f, 0.f, 0.f};
    #pragma unroll
    for (int nt = 0; nt < 32; ++nt) {
        short8 b0 = *(const short8*)&Wlds[((nt * 8 + quad) * 16 + n16) * 8];
        short8 b1 = *(const short8*)&Wlds[((nt * 8 + 4 + quad) * 16 + n16) * 8];
        acc[nt] = __builtin_amdgcn_mfma_f32_16x16x32_bf16(a0, b0, acc[nt], 0, 0, 0);
        acc[nt] = __builtin_amdgcn_mfma_f32_16x16x32_bf16(a1, b1, acc[nt], 0, 0, 0);
    }

    // LN over 512 per row; rows live as (quad, reg) across 16 lanes
    float s[4], s2[4];
    #pragma unroll
    for (int r = 0; r < 4; ++r) { s[r] = 0.f; s2[r] = 0.f; }
    #pragma unroll
    for (int nt = 0; nt < 32; ++nt)
        #pragma unroll
        for (int r = 0; r < 4; ++r) {
            float v = acc[nt][r];
            s[r] += v; s2[r] += v * v;
        }
    #pragma unroll
    for (int off = 1; off <= 8; off <<= 1)
        #pragma unroll
        for (int r = 0; r < 4; ++r) {
            s[r]  += __shfl_xor(s[r],  off, 64);
            s2[r] += __shfl_xor(s2[r], off, 64);
        }
    float mean[4], rstd[4];
    #pragma unroll
    for (int r = 0; r < 4; ++r) {
        mean[r] = s[r] * (1.f / 512.f);
        float var = s2[r] * (1.f / 512.f) - mean[r] * mean[r];
        rstd[r] = rsqrtf(var + EPSN);
    }

    const float sc = scale[0];
    const size_t rbase = (size_t)rowtile * 16 + quad * 4;
    #pragma unroll 8
    for (int nt = 0; nt < 32; ++nt) {
        int col = nt * 16 + n16;
        float gm = glds[col], bt = blds[col];
        #pragma unroll
        for (int r = 0; r < 4; ++r) {
            size_t idx = (rbase + r) * 512 + col;
            out[idx] = x[idx] + sc * ((acc[nt][r] - mean[r]) * rstd[r] * gm + bt);
        }
    }
}

extern "C" void kernel_launch(void* const* d_in, const int* in_sizes, int n_in,
                              void* d_out, int out_size, void* d_ws, size_t ws_size,
                              hipStream_t stream) {
    const float* x         = (const float*)d_in[0];
    const float* w_f       = (const float*)d_in[1];
    const float* w_h       = (const float*)d_in[2];
    const float* w_fgh     = (const float*)d_in[3];
    const float* gamma_f   = (const float*)d_in[4];
    const float* beta_f    = (const float*)d_in[5];
    const float* gamma_h   = (const float*)d_in[6];
    const float* beta_h    = (const float*)d_in[7];
    const float* gamma_fgh = (const float*)d_in[8];
    const float* beta_fgh  = (const float*)d_in[9];
    const float* scale     = (const float*)d_in[10];
    float* out = (float*)d_out;

    float* ws = (float*)d_ws;
    float* g  = ws;                            // 16 MB fp32
    float* h  = ws + (size_t)65536 * 64;       // 16 MB fp32
    unsigned short* tm = (unsigned short*)(ws + (size_t)2 * 65536 * 64);  // 8.4 MB bf16

    k1_gemm_ln<<<512, 256, 0, stream>>>(x, w_f, w_h, gamma_f, beta_f,
                                        gamma_h, beta_h, g, h);
    k2_softmax<<<1024, 256, 0, stream>>>(g, h, tm);
    k3_gemm_ln_res<<<1024, 256, 0, stream>>>(tm, w_fgh, gamma_fgh, beta_fgh,
                                             scale, x, out);
}

// Round 3
// 335.482 us; speedup vs baseline: 2.8192x; 1.1585x over previous
//
#include <hip/hip_runtime.h>

#define EPSN 1e-3f

typedef __attribute__((ext_vector_type(8))) short short8;
typedef __attribute__((ext_vector_type(4))) float floatx4;

__device__ __forceinline__ unsigned f2bf_pack(float a, float b) {
    unsigned ua = __builtin_bit_cast(unsigned, a);
    ua += 0x7FFF + ((ua >> 16) & 1);
    unsigned ub = __builtin_bit_cast(unsigned, b);
    ub += 0x7FFF + ((ub >> 16) & 1);
    return (ua >> 16) | (ub & 0xFFFF0000u);
}
__device__ __forceinline__ unsigned short f2bf(float f) {
    unsigned u = __builtin_bit_cast(unsigned, f);
    u += 0x7FFF + ((u >> 16) & 1);
    return (unsigned short)(u >> 16);
}
__device__ __forceinline__ float bf2f(unsigned short u) {
    unsigned v = ((unsigned)u) << 16;
    return __builtin_bit_cast(float, v);
}

// ---------------- Kernel 0: weights fp32 -> bf16 MFMA B-frag layout ----------
// Wgh: n in [0,128) (0..63 = w_f, 64..127 = w_h), k in [0,512).
//   Wgh[((ntile*64 + k8)*16 + n16)*8 + j] = W[k8*8+j][ntile*16+n16]
// Wf3: n in [0,512), k in [0,64).
//   Wf3[((ntile*8 + k8)*16 + n16)*8 + j] = w_fgh[k8*8+j][ntile*16+n16]
__global__ void k0_convert(const float* __restrict__ w_f,
                           const float* __restrict__ w_h,
                           const float* __restrict__ w_fgh,
                           unsigned short* __restrict__ Wgh,
                           unsigned short* __restrict__ Wf3)
{
    int tid = blockIdx.x * 256 + threadIdx.x;
    if (tid < 8192) {
        int n16 = tid & 15, k8 = (tid >> 4) & 63, ntile = tid >> 10;
        int n = ntile * 16 + n16;
        const float* src = (n < 64) ? (w_f + n) : (w_h + (n - 64));
        unsigned short o[8];
        #pragma unroll
        for (int j = 0; j < 8; ++j) o[j] = f2bf(src[(size_t)(k8 * 8 + j) * 64]);
        *(uint4*)&Wgh[(size_t)tid * 8] = *(const uint4*)o;
    } else if (tid < 12288) {
        int id = tid - 8192;
        int n16 = id & 15, k8 = (id >> 4) & 7, ntile = id >> 7;
        int n = ntile * 16 + n16;
        unsigned short o[8];
        #pragma unroll
        for (int j = 0; j < 8; ++j) o[j] = f2bf(w_fgh[(size_t)(k8 * 8 + j) * 512 + n]);
        *(uint4*)&Wf3[(size_t)id * 8] = *(const uint4*)o;
    }
}

// ---------------- Kernel 1: x @ (w_f|w_h) + fused LN -> g (fp32), h (bf16) ---
// Zero LDS, zero barriers. Block 256 (4 waves), 128 rows/block, 32 rows/wave.
// A-frags built in-register from coalesced x reads; B-frags from global Wgh.
// LN(64) per row-half entirely in-register via 16-lane shfl_xor.
__global__ __launch_bounds__(256, 3) void k1_gemm_ln(
    const float* __restrict__ x,
    const unsigned short* __restrict__ Wgh,
    const float* __restrict__ gamma_f, const float* __restrict__ beta_f,
    const float* __restrict__ gamma_h, const float* __restrict__ beta_h,
    float* __restrict__ g_out, unsigned short* __restrict__ h_out)
{
    const int t = threadIdx.x;
    const int lane = t & 63;
    const int wv = t >> 6;
    const int quad = lane >> 4;
    const int n16 = lane & 15;
    const int row_base = blockIdx.x * 128 + wv * 32;

    floatx4 acc[2][8];
    #pragma unroll
    for (int rt = 0; rt < 2; ++rt)
        #pragma unroll
        for (int ct = 0; ct < 8; ++ct) acc[rt][ct] = (floatx4){0.f, 0.f, 0.f, 0.f};

    const float* xrow = x + (size_t)(row_base + n16) * 512 + quad * 8;

    #pragma unroll 2
    for (int c = 0; c < 16; ++c) {
        short8 a[2];
        #pragma unroll
        for (int rt = 0; rt < 2; ++rt) {
            const float4* p = (const float4*)(xrow + rt * 16 * 512 + c * 32);
            float4 u = p[0], v = p[1];
            union { short8 s; uint4 q; } cvt;
            cvt.q = make_uint4(f2bf_pack(u.x, u.y), f2bf_pack(u.z, u.w),
                               f2bf_pack(v.x, v.y), f2bf_pack(v.z, v.w));
            a[rt] = cvt.s;
        }
        #pragma unroll
        for (int ct = 0; ct < 8; ++ct) {
            short8 b = *(const short8*)&Wgh[(size_t)(((ct * 64) + c * 4 + quad) * 16 + n16) * 8];
            acc[0][ct] = __builtin_amdgcn_mfma_f32_16x16x32_bf16(a[0], b, acc[0][ct], 0, 0, 0);
            acc[1][ct] = __builtin_amdgcn_mfma_f32_16x16x32_bf16(a[1], b, acc[1][ct], 0, 0, 0);
        }
    }

    // Epilogue: per-wave in-register LN over each 64-col half.
    #pragma unroll
    for (int rt = 0; rt < 2; ++rt) {
        #pragma unroll
        for (int half = 0; half < 2; ++half) {
            float s[4] = {0.f, 0.f, 0.f, 0.f}, s2[4] = {0.f, 0.f, 0.f, 0.f};
            #pragma unroll
            for (int c0 = 0; c0 < 4; ++c0) {
                int ct = half * 4 + c0;
                #pragma unroll
                for (int r = 0; r < 4; ++r) {
                    float v = acc[rt][ct][r];
                    s[r] += v; s2[r] += v * v;
                }
            }
            #pragma unroll
            for (int off = 1; off <= 8; off <<= 1)
                #pragma unroll
                for (int r = 0; r < 4; ++r) {
                    s[r]  += __shfl_xor(s[r],  off, 64);
                    s2[r] += __shfl_xor(s2[r], off, 64);
                }
            float mean[4], rstd[4];
            #pragma unroll
            for (int r = 0; r < 4; ++r) {
                mean[r] = s[r] * (1.f / 64.f);
                float var = s2[r] * (1.f / 64.f) - mean[r] * mean[r];
                rstd[r] = rsqrtf(var + EPSN);
            }
            #pragma unroll
            for (int c0 = 0; c0 < 4; ++c0) {
                int ct = half * 4 + c0;
                int col = c0 * 16 + n16;
                float gm = half ? gamma_h[col] : gamma_f[col];
                float bt = half ? beta_h[col]  : beta_f[col];
                #pragma unroll
                for (int r = 0; r < 4; ++r) {
                    int row = row_base + rt * 16 + quad * 4 + r;
                    float v = (acc[rt][ct][r] - mean[r]) * rstd[r] * gm + bt;
                    if (half == 0)
                        g_out[(size_t)row * 64 + col] = v;
                    else
                        h_out[(size_t)row * 64 + col] = f2bf(v);
                }
            }
        }
    }
}

// ---------------- Kernel 2: softmax over H of f*g, times h -> t (bf16 row-major)
__global__ __launch_bounds__(256, 4) void k2_softmax(
    const float* __restrict__ g_in,
    const unsigned short* __restrict__ h_in,
    unsigned short* __restrict__ t_out)
{
    __shared__ float S[64 * 64];
    __shared__ float Hm[64 * 64];
    __shared__ float pmax[4 * 64];
    __shared__ float psum[4 * 64];
    __shared__ float colmax[64];
    __shared__ float colinv[64];

    const int t = threadIdx.x;
    const int b = blockIdx.x >> 6;
    const int w = blockIdx.x & 63;
    const size_t base1 = (size_t)(b * 64 + w) * 4096;

    #pragma unroll
    for (int i = 0; i < 16; ++i) {
        int e = t + i * 256;
        int hh = e >> 6, ii = e & 63;
        size_t idx2 = ((size_t)((b * 64 + hh) * 64 + w)) * 64 + ii;
        S[e]  = g_in[base1 + e] * g_in[idx2];
        Hm[e] = bf2f(h_in[idx2]);
    }
    __syncthreads();

    const int q = t >> 6;
    const int i = t & 63;
    float m = -1e30f;
    #pragma unroll
    for (int r = 0; r < 16; ++r)
        m = fmaxf(m, S[(q * 16 + r) * 64 + i]);
    pmax[q * 64 + i] = m;
    __syncthreads();
    if (t < 64)
        colmax[i] = fmaxf(fmaxf(pmax[i], pmax[64 + i]),
                          fmaxf(pmax[128 + i], pmax[192 + i]));
    __syncthreads();
    const float cm = colmax[i];
    float s = 0.f;
    #pragma unroll
    for (int r = 0; r < 16; ++r) {
        int idx = (q * 16 + r) * 64 + i;
        float e = __expf(S[idx] - cm);
        S[idx] = e;
        s += e;
    }
    psum[q * 64 + i] = s;
    __syncthreads();
    if (t < 64)
        colinv[i] = 1.f / (psum[i] + psum[64 + i] + psum[128 + i] + psum[192 + i]);
    __syncthreads();
    const float ci = colinv[i];
    #pragma unroll
    for (int r = 0; r < 16; ++r) {
        int hh = q * 16 + r;
        int idx = hh * 64 + i;
        size_t row_g = (size_t)((b * 64 + hh) * 64 + w);
        t_out[row_g * 64 + i] = f2bf(S[idx] * ci * Hm[idx]);
    }
}

// ---------------- Kernel 3: t @ w_fgh + LN + scale + residual ----------------
// Block 256 (4 waves): 2 rowtiles x 2 col-halves (256 cols/wave). B-frags from
// global Wf3. Cross-wave LN pairing via tiny LDS. Epilogue via per-wave 8KB
// bounce -> 512B-contiguous x reads and out writes.
__global__ __launch_bounds__(256, 4) void k3_gemm_ln_res(
    const unsigned short* __restrict__ tmat,
    const unsigned short* __restrict__ Wf3,
    const float* __restrict__ gamma, const float* __restrict__ beta,
    const float* __restrict__ scale,
    const float* __restrict__ x,
    float* __restrict__ out)
{
    __shared__ float bounce[4][16 * 132];   // 33.8 KB
    __shared__ float2 exch[4][16];

    const int t = threadIdx.x;
    const int lane = t & 63;
    const int wv = t >> 6;
    const int quad = lane >> 4;
    const int n16 = lane & 15;
    const int rowtile = blockIdx.x * 2 + (wv >> 1);
    const int half = wv & 1;

    const unsigned short* trow = tmat + (size_t)(rowtile * 16 + n16) * 64 + quad * 8;
    short8 a0 = *(const short8*)trow;
    short8 a1 = *(const short8*)(trow + 32);

    floatx4 acc[16];
    #pragma unroll
    for (int nt = 0; nt < 16; ++nt) acc[nt] = (floatx4){0.f, 0.f, 0.f, 0.f};
    #pragma unroll
    for (int nt = 0; nt < 16; ++nt) {
        int ngt = half * 16 + nt;
        short8 b0 = *(const short8*)&Wf3[(size_t)((ngt * 8 + quad) * 16 + n16) * 8];
        short8 b1 = *(const short8*)&Wf3[(size_t)((ngt * 8 + 4 + quad) * 16 + n16) * 8];
        acc[nt] = __builtin_amdgcn_mfma_f32_16x16x32_bf16(a0, b0, acc[nt], 0, 0, 0);
        acc[nt] = __builtin_amdgcn_mfma_f32_16x16x32_bf16(a1, b1, acc[nt], 0, 0, 0);
    }

    // Partial LN sums over this wave's 256 cols, reduce across 16 lanes.
    float s[4] = {0.f, 0.f, 0.f, 0.f}, s2[4] = {0.f, 0.f, 0.f, 0.f};
    #pragma unroll
    for (int nt = 0; nt < 16; ++nt)
        #pragma unroll
        for (int r = 0; r < 4; ++r) {
            float v = acc[nt][r];
            s[r] += v; s2[r] += v * v;
        }
    #pragma unroll
    for (int off = 1; off <= 8; off <<= 1)
        #pragma unroll
        for (int r = 0; r < 4; ++r) {
            s[r]  += __shfl_xor(s[r],  off, 64);
            s2[r] += __shfl_xor(s2[r], off, 64);
        }
    if (n16 == 0) {
        #pragma unroll
        for (int r = 0; r < 4; ++r)
            exch[wv][quad * 4 + r] = make_float2(s[r], s2[r]);
    }
    __syncthreads();
    float mean[4], rstd[4];
    #pragma unroll
    for (int r = 0; r < 4; ++r) {
        float2 o = exch[wv ^ 1][quad * 4 + r];
        float st = s[r] + o.x, st2 = s2[r] + o.y;
        mean[r] = st * (1.f / 512.f);
        float var = st2 * (1.f / 512.f) - mean[r] * mean[r];
        rstd[r] = rsqrtf(var + EPSN);
    }
    const float sc = scale[0];

    #pragma unroll
    for (int chunk = 0; chunk < 2; ++chunk) {
        __syncthreads();   // WAR vs previous chunk's reads (uniform across block)
        #pragma unroll
        for (int n0 = 0; n0 < 8; ++n0) {
            int nt = chunk * 8 + n0;
            int col = half * 256 + nt * 16 + n16;
            float gm = gamma[col], bt = beta[col];
            #pragma unroll
            for (int r = 0; r < 4; ++r)
                bounce[wv][(quad * 4 + r) * 132 + n0 * 16 + n16] =
                    sc * ((acc[nt][r] - mean[r]) * rstd[r] * gm + bt);
        }
        __syncthreads();
        #pragma unroll
        for (int pass = 0; pass < 8; ++pass) {
            int row = pass * 2 + (lane >> 5);
            int coff = (lane & 31) * 4;
            float4 v = *(const float4*)&bounce[wv][row * 132 + coff];
            size_t gidx = ((size_t)rowtile * 16 + row) * 512 + half * 256 + chunk * 128 + coff;
            float4 xv = *(const float4*)&x[gidx];
            float4 o;
            o.x = xv.x + v.x; o.y = xv.y + v.y; o.z = xv.z + v.z; o.w = xv.w + v.w;
            *(float4*)&out[gidx] = o;
        }
    }
}

extern "C" void kernel_launch(void* const* d_in, const int* in_sizes, int n_in,
                              void* d_out, int out_size, void* d_ws, size_t ws_size,
                              hipStream_t stream) {
    const float* x         = (const float*)d_in[0];
    const float* w_f       = (const float*)d_in[1];
    const float* w_h       = (const float*)d_in[2];
    const float* w_fgh     = (const float*)d_in[3];
    const float* gamma_f   = (const float*)d_in[4];
    const float* beta_f    = (const float*)d_in[5];
    const float* gamma_h   = (const float*)d_in[6];
    const float* beta_h    = (const float*)d_in[7];
    const float* gamma_fgh = (const float*)d_in[8];
    const float* beta_fgh  = (const float*)d_in[9];
    const float* scale     = (const float*)d_in[10];
    float* out = (float*)d_out;

    char* wsb = (char*)d_ws;
    float* g            = (float*)wsb;                            // 16 MB
    unsigned short* h   = (unsigned short*)(wsb + 16777216);      // 8 MB
    unsigned short* tm  = (unsigned short*)(wsb + 25165824);      // 8 MB
    unsigned short* Wgh = (unsigned short*)(wsb + 33554432);      // 128 KB
    unsigned short* Wf3 = (unsigned short*)(wsb + 33685504);      // 64 KB

    k0_convert<<<48, 256, 0, stream>>>(w_f, w_h, w_fgh, Wgh, Wf3);
    k1_gemm_ln<<<512, 256, 0, stream>>>(x, Wgh, gamma_f, beta_f,
                                        gamma_h, beta_h, g, h);
    k2_softmax<<<1024, 256, 0, stream>>>(g, h, tm);
    k3_gemm_ln_res<<<2048, 256, 0, stream>>>(tm, Wf3, gamma_fgh, beta_fgh,
                                             scale, x, out);
}